// Round 4
// baseline (52.404 us; speedup 1.0000x reference)
//
#include <hip/hip_runtime.h>
#include <cmath>

// VarRateResampler ratio=2: per (b,t) two 21-tap FIRs, polyphase rows chosen
// by an NCO with step s = 64 + acc_phase. Closed form for the NCO state
// entering step t:  a_t = ceil(t*Q/s)*s - t*Q  (invariant a in [0,Q)).
// Single flat kernel: each thread produces 8 consecutive t of one row.
//   - x window (28 floats) via 7 aligned global float4 loads (no LDS/barrier)
//   - NCO seed via one f64 ceil + exact reference f32 recurrence for 7 steps
//   - taps via wave-uniform scalar loads (s_load, once per wave)
//   - output via 4 nontemporal float4 stores
// Round-3 evidence: LDS+barrier structure stalled at 2.4 TB/s while the
// harness fill kernel streams 6.7 TB/s on the same buffer.

#define QQ   128
#define LT   21
#define TT   4096
#define TPT  8                 // t per thread
#define BLK  256
#define TILE (BLK * TPT)       // 2048 t per block

typedef float float4n __attribute__((ext_vector_type(4)));

__global__ __launch_bounds__(BLK) void fir_kernel(
    const float* __restrict__ x,
    const float* __restrict__ hs,
    const float* __restrict__ accp,
    float*       __restrict__ y)
{
    const int b  = blockIdx.y;
    const int t0 = blockIdx.x * TILE + threadIdx.x * TPT;
    const size_t row = (size_t)b * TT;

    // ---- x window x[t0-20 .. t0+7] : 28 floats, 16B-aligned when base>=0 ----
    float xr[28];
    const int base = t0 - 20;
    if (base >= 0) {
        const float4* src = (const float4*)(x + row + base);  // (8m-20)%4==0
        #pragma unroll
        for (int q = 0; q < 7; ++q) {
            float4 v = src[q];
            xr[4*q+0] = v.x; xr[4*q+1] = v.y; xr[4*q+2] = v.z; xr[4*q+3] = v.w;
        }
    } else {                        // only threads 0..2 of each row's block 0
        #pragma unroll
        for (int i = 0; i < 28; ++i) {
            int gt = base + i;
            xr[i] = (gt >= 0) ? x[row + gt] : 0.0f;   // fifo zero-init
        }
    }

    // ---- NCO: f64 closed-form seed, then exact reference f32 recurrence ----
    const float sf = 64.0f + accp[0];                 // step_inc (f32)
    const double s = (double)sf;
    const double tq0 = (double)t0 * 128.0;
    float a = (float)(__builtin_ceil(tq0 / s) * s - tq0);  // acc entering t0

    int i0[TPT], i1[TPT];
    #pragma unroll
    for (int k = 0; k < TPT; ++k) {
        bool  v0   = a < 128.0f;                      // slot 0
        float ind0 = v0 ? a : -1.0f;
        float ap   = v0 ? a + sf : a;
        bool  v1   = ap < 128.0f;                     // slot 1
        float ind1 = v1 ? ap : -1.0f;
        float an   = v1 ? ap + sf : ap;
        a = an - 128.0f;                              // wrap
        i0[k] = min((int)rintf(ind0), QQ - 1);        // -1 => NaN row
        i1[k] = min((int)rintf(ind1), QQ - 1);
    }

    // ---- wave-uniform fast path check ----
    bool uni = true;
    #pragma unroll
    for (int k = 1; k < TPT; ++k) uni &= (i0[k] == i0[0]) & (i1[k] == i1[0]);
    const int f0 = __builtin_amdgcn_readfirstlane(i0[0]);
    const int f1 = __builtin_amdgcn_readfirstlane(i1[0]);
    uni &= (i0[0] == f0) & (i1[0] == f1);

    float out[2 * TPT];

    if (__all(uni) && f0 >= 0 && f1 >= 0) {
        // taps are wave-uniform -> scalar loads into SGPRs, once per wave
        const float* __restrict__ h0 = hs + (size_t)f0 * LT;
        const float* __restrict__ h1 = hs + (size_t)f1 * LT;
        #pragma unroll
        for (int k = 0; k < TPT; ++k) {
            float a0 = 0.0f, a1 = 0.0f;
            #pragma unroll
            for (int l = 0; l < LT; ++l) {
                a0 = fmaf(h0[l], xr[k + l], a0);
                a1 = fmaf(h1[l], xr[k + l], a1);
            }
            out[2*k]     = a0;
            out[2*k + 1] = a1;
        }
    } else {
        // generic per-lane gather path (any acc_phase); correctness-only
        const float NaNf = __int_as_float(0x7fc00000);
        #pragma unroll
        for (int k = 0; k < TPT; ++k) {
            const int r0 = i0[k], r1 = i1[k];
            float a0 = 0.0f, a1 = 0.0f;
            if (r0 >= 0) {
                const float* hp = hs + (size_t)r0 * LT;
                #pragma unroll
                for (int l = 0; l < LT; ++l) a0 = fmaf(hp[l], xr[k + l], a0);
            } else a0 = NaNf;
            if (r1 >= 0) {
                const float* hp = hs + (size_t)r1 * LT;
                #pragma unroll
                for (int l = 0; l < LT; ++l) a1 = fmaf(hp[l], xr[k + l], a1);
            } else a1 = NaNf;
            out[2*k]     = a0;
            out[2*k + 1] = a1;
        }
    }

    // ---- write (B, T, 2): 16 floats = 4 float4, 64B contiguous per lane ----
    float4n* yq = (float4n*)(y + (row + (size_t)t0) * 2);
    #pragma unroll
    for (int q = 0; q < 4; ++q) {
        float4n o = {out[4*q+0], out[4*q+1], out[4*q+2], out[4*q+3]};
        __builtin_nontemporal_store(o, yq + q);
    }
}

extern "C" void kernel_launch(void* const* d_in, const int* in_sizes, int n_in,
                              void* d_out, int out_size, void* d_ws, size_t ws_size,
                              hipStream_t stream) {
    const float* x    = (const float*)d_in[0];   // (B, 4096) f32
    const float* hs   = (const float*)d_in[1];   // (128, 21) f32
    const float* accp = (const float*)d_in[2];   // scalar f32
    float* y = (float*)d_out;                    // (B, 4096, 2) f32

    const int B = in_sizes[0] / TT;

    dim3 grid(TT / TILE, B);                     // (2, 2048)
    fir_kernel<<<grid, BLK, 0, stream>>>(x, hs, accp, y);
}

// Round 5
// 23.249 us; speedup vs baseline: 2.2540x; 2.2540x over previous
//
#include <hip/hip_runtime.h>
#include <cmath>

// VarRateResampler ratio=2: per (b,t) two 21-tap FIRs, polyphase rows chosen
// by an NCO with step s = 64 + acc_phase. Closed form for the NCO state
// entering step t:  a_t = ceil(t*Q/s)*s - t*Q  (invariant a in [0,Q)).
// Flat kernel, TPT=4: each thread produces 4 consecutive t of one row.
//  - x window (24 floats, 16B-aligned) via 6 global float4 loads; per
//    instruction the wave reads a contiguous 1 KB span (no LDS, no barrier)
//  - NCO seeded in f64 closed form + exact reference f32 recurrence
//  - taps via wave-uniform scalar loads (s_load, once per wave)
//  - 2 NT float4 stores per lane at 32B lane-stride (round-3 proven: <=5%
//    write amplification; round-4's 64B stride caused 1.8x -> reverted)

#define QQ   128
#define LT   21
#define TT   4096
#define TPT  4                 // t per thread
#define BLK  256
#define TILE (BLK * TPT)       // 1024 t per block

typedef float float4n __attribute__((ext_vector_type(4)));

__global__ __launch_bounds__(BLK) void fir_kernel(
    const float* __restrict__ x,
    const float* __restrict__ hs,
    const float* __restrict__ accp,
    float*       __restrict__ y)
{
    const int b  = blockIdx.y;
    const int t0 = blockIdx.x * TILE + threadIdx.x * TPT;
    const size_t row = (size_t)b * TT;

    // ---- x window x[t0-20 .. t0+3] : 24 floats, base (4m-20) is 16B-aligned ----
    float xr[24];
    const int base = t0 - 20;
    if (base >= 0) {
        const float4* src = (const float4*)(x + row + base);
        #pragma unroll
        for (int q = 0; q < 6; ++q) {
            float4 v = src[q];
            xr[4*q+0] = v.x; xr[4*q+1] = v.y; xr[4*q+2] = v.z; xr[4*q+3] = v.w;
        }
    } else {                        // only threads 0..4 of each row's first block
        #pragma unroll
        for (int i = 0; i < 24; ++i) {
            int gt = base + i;
            xr[i] = (gt >= 0) ? x[row + gt] : 0.0f;   // fifo zero-init
        }
    }

    // ---- NCO: f64 closed-form seed, then exact reference f32 recurrence ----
    const float sf = 64.0f + accp[0];                 // step_inc (f32)
    const double s = (double)sf;
    const double tq0 = (double)t0 * 128.0;
    float a = (float)(__builtin_ceil(tq0 / s) * s - tq0);  // acc entering t0

    int i0[TPT], i1[TPT];
    #pragma unroll
    for (int k = 0; k < TPT; ++k) {
        bool  v0   = a < 128.0f;                      // slot 0
        float ind0 = v0 ? a : -1.0f;
        float ap   = v0 ? a + sf : a;
        bool  v1   = ap < 128.0f;                     // slot 1
        float ind1 = v1 ? ap : -1.0f;
        float an   = v1 ? ap + sf : ap;
        a = an - 128.0f;                              // wrap
        i0[k] = min((int)rintf(ind0), QQ - 1);        // -1 => NaN row
        i1[k] = min((int)rintf(ind1), QQ - 1);
    }

    // ---- wave-uniform fast path check ----
    bool uni = true;
    #pragma unroll
    for (int k = 1; k < TPT; ++k) uni &= (i0[k] == i0[0]) & (i1[k] == i1[0]);
    const int f0 = __builtin_amdgcn_readfirstlane(i0[0]);
    const int f1 = __builtin_amdgcn_readfirstlane(i1[0]);
    uni &= (i0[0] == f0) & (i1[0] == f1);

    float out[2 * TPT];

    if (__all(uni) && f0 >= 0 && f1 >= 0) {
        // taps are wave-uniform -> scalar loads into SGPRs, once per wave
        const float* __restrict__ h0 = hs + (size_t)f0 * LT;
        const float* __restrict__ h1 = hs + (size_t)f1 * LT;
        #pragma unroll
        for (int k = 0; k < TPT; ++k) {
            float a0 = 0.0f, a1 = 0.0f;
            #pragma unroll
            for (int l = 0; l < LT; ++l) {
                a0 = fmaf(h0[l], xr[k + l], a0);
                a1 = fmaf(h1[l], xr[k + l], a1);
            }
            out[2*k]     = a0;
            out[2*k + 1] = a1;
        }
    } else {
        // generic per-lane gather path (any acc_phase); correctness-only
        const float NaNf = __int_as_float(0x7fc00000);
        #pragma unroll
        for (int k = 0; k < TPT; ++k) {
            const int r0 = i0[k], r1 = i1[k];
            float a0 = 0.0f, a1 = 0.0f;
            if (r0 >= 0) {
                const float* hp = hs + (size_t)r0 * LT;
                #pragma unroll
                for (int l = 0; l < LT; ++l) a0 = fmaf(hp[l], xr[k + l], a0);
            } else a0 = NaNf;
            if (r1 >= 0) {
                const float* hp = hs + (size_t)r1 * LT;
                #pragma unroll
                for (int l = 0; l < LT; ++l) a1 = fmaf(hp[l], xr[k + l], a1);
            } else a1 = NaNf;
            out[2*k]     = a0;
            out[2*k + 1] = a1;
        }
    }

    // ---- write (B, T, 2): 8 floats = 2 float4, 32B lane-stride ----
    float4n* yq = (float4n*)(y + (row + (size_t)t0) * 2);
    float4n o0 = {out[0], out[1], out[2], out[3]};
    float4n o1 = {out[4], out[5], out[6], out[7]};
    __builtin_nontemporal_store(o0, yq + 0);
    __builtin_nontemporal_store(o1, yq + 1);
}

extern "C" void kernel_launch(void* const* d_in, const int* in_sizes, int n_in,
                              void* d_out, int out_size, void* d_ws, size_t ws_size,
                              hipStream_t stream) {
    const float* x    = (const float*)d_in[0];   // (B, 4096) f32
    const float* hs   = (const float*)d_in[1];   // (128, 21) f32
    const float* accp = (const float*)d_in[2];   // scalar f32
    float* y = (float*)d_out;                    // (B, 4096, 2) f32

    const int B = in_sizes[0] / TT;

    dim3 grid(TT / TILE, B);                     // (4, 2048)
    fir_kernel<<<grid, BLK, 0, stream>>>(x, hs, accp, y);
}